// Round 4
// baseline (5886.440 us; speedup 1.0000x reference)
//
#include <hip/hip_runtime.h>

// FeedBack LSTM: 128 warmup + 31 AR steps, B=4096, UNITS=512, FEAT=12.
//  - AR feedback folded into weights: z = h@(U + Wd@W) + (b + bd@W) (exact).
//  - Per step: [4096,512]@[512,2048] bf16 MFMA GEMM fused with gate math.
//  - R2: reg-staged 2-deep prefetch pipeline, XOR-swizzled LDS, z-through-LDS.
//  - R3: pred via one MFMA kernel over stored h-history (hall ring).
//  - R4: persistent cooperative kernel for all 159 steps: c lives in VGPRs
//    (16/thread, zero HBM traffic), Ut/Uta L2-hot, zero launch gaps; steps
//    synced by per-mt-group (16 block) monotonic atomic barriers with
//    agent-scope release/acquire. Fallback to per-step path if coop launch
//    is rejected.

typedef __bf16 bf16;
typedef __attribute__((ext_vector_type(8))) __bf16 bf16x8;
typedef __attribute__((ext_vector_type(4))) float f32x4;

#define NB    4096
#define TSEQ  128
#define FEAT  12
#define UNITS 512
#define NZ    2048
#define OUTS  32
#define NSTEP (TSEQ + OUTS - 1)   // 159

#define BM 128
#define BK 64

// workspace layout (bytes)
#define OFF_UT   ((size_t)0)
#define OFF_UTA  (OFF_UT  + (size_t)NZ*UNITS*2)    // 2 MB
#define OFF_WT   (OFF_UTA + (size_t)NZ*UNITS*2)    // 2 MB
#define OFF_B2   (OFF_WT  + (size_t)NZ*32*2)       // 128 KB
#define OFF_WDT  (OFF_B2  + (size_t)NZ*4)          // 8 KB
#define OFF_H0   (OFF_WDT + (size_t)16*UNITS*2)    // 16 KB
#define OFF_H1   (OFF_H0  + (size_t)NB*UNITS*2)    // 4 MB
#define OFF_C    (OFF_H1  + (size_t)NB*UNITS*2)    // 4 MB
#define OFF_BAR  (OFF_C   + (size_t)NB*UNITS*4)    // +8 MB
#define WS_NEED  (OFF_BAR + 4096)
#define OFF_HALL (WS_NEED)
#define HALL_SL  ((size_t)NB*UNITS)
#define WS_BIG   (OFF_HALL + (size_t)OUTS*NB*UNITS*2)   // +128 MB

__device__ __forceinline__ float fast_exp2(float x){ return __builtin_amdgcn_exp2f(x); }
__device__ __forceinline__ float fast_rcp (float x){ return __builtin_amdgcn_rcpf(x); }
__device__ __forceinline__ float sigm_(float x){ return fast_rcp(1.f + fast_exp2(-1.4426950408889634f*x)); }
__device__ __forceinline__ float tanh_(float x){ return 1.f - 2.f*fast_rcp(1.f + fast_exp2(2.8853900817779268f*x)); }

// ---------------- prep: U^T and (U + Wd@W)^T in bf16 --------------------
__global__ void prep_u_kernel(const float* __restrict__ U, const float* __restrict__ W,
                              const float* __restrict__ Wd,
                              bf16* __restrict__ Ut, bf16* __restrict__ Uta){
  __shared__ float su[64][65];
  __shared__ float sa[64][65];
  const int n0 = blockIdx.x * 64;
  const int k0 = blockIdx.y * 64;
  const int tx = threadIdx.x & 63;
  const int rr = threadIdx.x >> 6;
  #pragma unroll 4
  for (int it = 0; it < 16; ++it){
    int k = it*4 + rr;
    float u = U[(size_t)(k0+k)*NZ + n0 + tx];
    float a = u;
    #pragma unroll
    for (int j = 0; j < FEAT; ++j) a += Wd[(k0+k)*FEAT + j] * W[(size_t)j*NZ + n0 + tx];
    su[tx][k] = u;
    sa[tx][k] = a;
  }
  __syncthreads();
  #pragma unroll 4
  for (int it = 0; it < 16; ++it){
    int nl = it*4 + rr;
    Ut [(size_t)(n0+nl)*UNITS + k0 + tx] = (bf16)su[nl][tx];
    Uta[(size_t)(n0+nl)*UNITS + k0 + tx] = (bf16)sa[nl][tx];
  }
}

// ------- prep: W^T (k-padded), b2 = b + bd@W, Wdt = Wd^T (bf16) ---------
__global__ void prep_w_kernel(const float* __restrict__ W, const float* __restrict__ b,
                              const float* __restrict__ bd, const float* __restrict__ Wd,
                              bf16* __restrict__ Wt, float* __restrict__ b2,
                              bf16* __restrict__ Wdt){
  const int n = blockIdx.x*256 + threadIdx.x;
  float acc = b[n];
  #pragma unroll
  for (int j = 0; j < FEAT; ++j){
    float w = W[(size_t)j*NZ + n];
    Wt[(size_t)n*32 + j] = (bf16)w;
    acc += bd[j] * w;
  }
  #pragma unroll
  for (int j = FEAT; j < 32; ++j) Wt[(size_t)n*32 + j] = (bf16)0.f;
  b2[n] = acc;
  if (n < UNITS){
    #pragma unroll
    for (int j = 0; j < FEAT; ++j) Wdt[(size_t)j*UNITS + n] = (bf16)Wd[(size_t)n*FEAT + j];
    #pragma unroll
    for (int j = FEAT; j < 16; ++j) Wdt[(size_t)j*UNITS + n] = (bf16)0.f;
  }
}

// ================= persistent all-steps kernel (cooperative) ============
__launch_bounds__(256, 2)
__global__ void lstm_persistent(bf16* __restrict__ hA,        // zeroed ping [NB,512]
                                bf16* __restrict__ hB,        // pong
                                bf16* __restrict__ hall,      // [OUTS][NB,512]
                                const bf16* __restrict__ Ut,
                                const bf16* __restrict__ Uta,
                                const float* __restrict__ b1, // [2048]
                                const float* __restrict__ b2, // [2048]
                                const float* __restrict__ x,  // [NB,TSEQ,FEAT]
                                const bf16* __restrict__ Wt,  // [2048][32]
                                unsigned* __restrict__ bar)   // [32] zeroed
{
  __shared__ alignas(16) char lds[65536];

  int bid = blockIdx.x;
  bid = (bid & 7) * 64 + (bid >> 3);          // XCD swizzle
  const int mt = bid >> 4;
  const int nu = bid & 15;
  const int m0 = mt * BM;

  const int tid  = threadIdx.x;
  const int lane = tid & 63;
  const int wid  = tid >> 6;
  const int wm   = wid >> 1, wn = wid & 1;
  const int l15  = lane & 15;
  const int kgrp = lane >> 4;
  const int l7   = lane & 7;
  const int l8   = lane >> 3;

  const int    aoff = (wid*32 + l8)*128 + ((l7 ^ l8) << 4);
  const size_t arow = (size_t)(m0 + wid*32 + l8)*UNITS + l7*8;  // + i*8*UNITS + k0
  int zcv[4];
  #pragma unroll
  for (int i = 0; i < 4; ++i){
    int lnl = wid*32 + i*8 + l8;
    zcv[i] = ((lnl & 3) << 9) + nu*32 + (lnl >> 2);
  }

  // hoisted constants: Wt fragments, x row offsets, biases (both phases)
  bf16x8 wq[4];
  int    xrow[4];
  #pragma unroll
  for (int f = 0; f < 4; ++f){
    int lnl = wn*64 + f*16 + l15;
    int zc  = ((lnl & 3) << 9) + nu*32 + (lnl >> 2);
    wq[f] = *reinterpret_cast<const bf16x8*>(Wt + (size_t)zc*32 + kgrp*8);
    xrow[f] = (m0 + wm*64 + f*16 + l15) * (TSEQ*FEAT);
  }
  const int eu  = tid & 31;
  const int erg = tid >> 5;
  const int cu  = nu*32 + eu;
  const float bI1 = b1[0*UNITS+cu], bF1 = b1[1*UNITS+cu], bG1 = b1[2*UNITS+cu], bO1 = b1[3*UNITS+cu];
  const float bI2 = b2[0*UNITS+cu], bF2 = b2[1*UNITS+cu], bG2 = b2[2*UNITS+cu], bO2 = b2[3*UNITS+cu];
  const int rbase = m0 + erg*16;

  float cc[16];
  #pragma unroll
  for (int r = 0; r < 16; ++r) cc[r] = 0.f;

  f32x4 acc[4][4];
  bf16x8 rA[2][4], rB[2][4];

  #pragma unroll 1
  for (int t = 0; t < NSTEP; ++t){
    const bool hasx = (t < TSEQ);
    const bf16* Bt = hasx ? Ut : Uta;
    const bf16* hi = (t < TSEQ) ? ((t & 1) ? hB : hA)
                                : hall + (size_t)(t - TSEQ)*HALL_SL;
    bf16* ho = (t < TSEQ-1) ? ((t & 1) ? hA : hB)
                            : hall + (size_t)(t - (TSEQ-1))*HALL_SL;

    // x fragments for this step (input-only: safe before barrier; hides spin)
    bf16x8 xa[4];
    if (hasx){
      #pragma unroll
      for (int f = 0; f < 4; ++f){
        const float* xr = x + xrow[f] + t*FEAT;
        bf16x8 v;
        #pragma unroll
        for (int j = 0; j < 8; ++j) v[j] = (bf16)0.f;
        if (kgrp == 0){
          float4 a = *reinterpret_cast<const float4*>(xr);
          float4 b = *reinterpret_cast<const float4*>(xr + 4);
          v[0]=(bf16)a.x; v[1]=(bf16)a.y; v[2]=(bf16)a.z; v[3]=(bf16)a.w;
          v[4]=(bf16)b.x; v[5]=(bf16)b.y; v[6]=(bf16)b.z; v[7]=(bf16)b.w;
        } else if (kgrp == 1){
          float4 a = *reinterpret_cast<const float4*>(xr + 8);
          v[0]=(bf16)a.x; v[1]=(bf16)a.y; v[2]=(bf16)a.z; v[3]=(bf16)a.w;
        }
        xa[f] = v;
      }
    }

    // ---- wait: producers of this step's h-input (16-block mt-group) ----
    if (t > 0){
      if (tid == 0){
        const unsigned tgt = 16u * (unsigned)t;
        while (__hip_atomic_load(&bar[mt], __ATOMIC_RELAXED, __HIP_MEMORY_SCOPE_AGENT) < tgt)
          __builtin_amdgcn_s_sleep(4);
        __builtin_amdgcn_fence(__ATOMIC_ACQUIRE, "agent");
      }
      __syncthreads();
    }

    auto load_set = [&](int s, int k0){
      #pragma unroll
      for (int i = 0; i < 4; ++i){
        rA[s][i] = *reinterpret_cast<const bf16x8*>(hi + arow + (size_t)i*8*UNITS + k0);
        rB[s][i] = *reinterpret_cast<const bf16x8*>(Bt + (size_t)zcv[i]*UNITS + k0 + l7*8);
      }
    };
    auto write_set = [&](int s, int bi){
      char* A = lds + (bi << 14);
      char* B = lds + 32768 + (bi << 14);
      #pragma unroll
      for (int i = 0; i < 4; ++i){
        *reinterpret_cast<bf16x8*>(A + aoff + i*1024) = rA[s][i];
        *reinterpret_cast<bf16x8*>(B + aoff + i*1024) = rB[s][i];
      }
    };
    auto compute = [&](int bi){
      const char* A = lds + (bi << 14);
      const char* B = lds + 32768 + (bi << 14);
      #pragma unroll
      for (int kk = 0; kk < 2; ++kk){
        const int sa = (((kk*4 + kgrp) ^ (l15 & 7)) << 4);
        bf16x8 af[4], bq[4];
        #pragma unroll
        for (int f = 0; f < 4; ++f){
          af[f] = *reinterpret_cast<const bf16x8*>(A + (wm*64 + f*16 + l15)*128 + sa);
          bq[f] = *reinterpret_cast<const bf16x8*>(B + (wn*64 + f*16 + l15)*128 + sa);
        }
        #pragma unroll
        for (int i = 0; i < 4; ++i)
          #pragma unroll
          for (int j = 0; j < 4; ++j)
            acc[i][j] = __builtin_amdgcn_mfma_f32_16x16x32_bf16(af[i], bq[j], acc[i][j], 0, 0, 0);
      }
    };

    #pragma unroll
    for (int i = 0; i < 4; ++i)
      #pragma unroll
      for (int j = 0; j < 4; ++j) acc[i][j] = f32x4{0.f,0.f,0.f,0.f};

    // ---- GEMM: 2-deep reg-staged pipeline over K=512 ----
    load_set(0, 0);
    load_set(1, BK);
    write_set(0, 0);
    asm volatile("s_waitcnt lgkmcnt(0)" ::: "memory");
    __builtin_amdgcn_sched_barrier(0);
    __builtin_amdgcn_s_barrier();

    #pragma unroll
    for (int kt = 0; kt < 8; ++kt){
      const int p = kt & 1;
      if (kt + 2 < 8) load_set(p, (kt+2)*BK);
      compute(p);
      if (kt < 7){
        write_set(p ^ 1, p ^ 1);
        asm volatile("s_waitcnt lgkmcnt(0)" ::: "memory");
        __builtin_amdgcn_sched_barrier(0);
        __builtin_amdgcn_s_barrier();
      }
    }

    if (hasx){
      #pragma unroll
      for (int i = 0; i < 4; ++i)
        #pragma unroll
        for (int j = 0; j < 4; ++j)
          acc[i][j] = __builtin_amdgcn_mfma_f32_16x16x32_bf16(xa[i], wq[j], acc[i][j], 0, 0, 0);
    }

    // ---- z through LDS ----
    asm volatile("s_waitcnt lgkmcnt(0)" ::: "memory");
    __builtin_amdgcn_sched_barrier(0);
    __builtin_amdgcn_s_barrier();

    #pragma unroll
    for (int fm = 0; fm < 4; ++fm){
      #pragma unroll
      for (int fn = 0; fn < 4; ++fn){
        int col  = wn*64 + fn*16 + l15;
        int srow = wm*16 + fm*4 + kgrp;
        *reinterpret_cast<f32x4*>(lds + col*512 + ((srow ^ (col & 7)) << 4)) = acc[fm][fn];
      }
    }
    asm volatile("s_waitcnt lgkmcnt(0)" ::: "memory");
    __builtin_amdgcn_sched_barrier(0);
    __builtin_amdgcn_s_barrier();

    const float bi_ = hasx ? bI1 : bI2;
    const float bf_ = hasx ? bF1 : bF2;
    const float bg_ = hasx ? bG1 : bG2;
    const float bo_ = hasx ? bO1 : bO2;

    #pragma unroll
    for (int q = 0; q < 4; ++q){
      const int s = erg*4 + q;
      f32x4 zi = *reinterpret_cast<const f32x4*>(lds + (eu*4+0)*512 + ((s ^ ((eu*4+0)&7)) << 4));
      f32x4 zf = *reinterpret_cast<const f32x4*>(lds + (eu*4+1)*512 + ((s ^ ((eu*4+1)&7)) << 4));
      f32x4 zg = *reinterpret_cast<const f32x4*>(lds + (eu*4+2)*512 + ((s ^ ((eu*4+2)&7)) << 4));
      f32x4 zo = *reinterpret_cast<const f32x4*>(lds + (eu*4+3)*512 + ((s ^ ((eu*4+3)&7)) << 4));
      #pragma unroll
      for (int rr2 = 0; rr2 < 4; ++rr2){
        int r = q*4 + rr2;
        float iv = sigm_(zi[rr2] + bi_);
        float fv = sigm_(zf[rr2] + bf_);
        float gv = tanh_(zg[rr2] + bg_);
        float ov = sigm_(zo[rr2] + bo_);
        float cn = fv*cc[r] + iv*gv;
        cc[r] = cn;
        ho[(size_t)(rbase + r)*UNITS + cu] = (bf16)(ov*tanh_(cn));
      }
    }

    // ---- arrive: my h-writes drained (vmcnt0 in syncthreads) + release ----
    if (t < NSTEP - 1){
      __syncthreads();
      if (tid == 0)
        __hip_atomic_fetch_add(&bar[mt], 1u, __ATOMIC_RELEASE, __HIP_MEMORY_SCOPE_AGENT);
    }
  }
}

// ---------------- per-step kernel (fallback path) -----------------------
template<int HAS_X>
__launch_bounds__(256, 2)
__global__ void lstm_step_kernel(const bf16* __restrict__ hin, bf16* __restrict__ hout,
                                 float* __restrict__ c,
                                 const bf16* __restrict__ Bt,
                                 const float* __restrict__ bias,
                                 const float* __restrict__ xt,
                                 const bf16* __restrict__ Wt)
{
  __shared__ alignas(16) char lds[65536];
  int bid = blockIdx.x;
  bid = (bid & 7) * 64 + (bid >> 3);
  const int mt = bid >> 4;
  const int nu = bid & 15;
  const int m0 = mt * BM;
  const int tid  = threadIdx.x;
  const int lane = tid & 63;
  const int wid  = tid >> 6;
  const int wm   = wid >> 1, wn = wid & 1;
  const int l15  = lane & 15;
  const int kgrp = lane >> 4;
  const int l7   = lane & 7;
  const int l8   = lane >> 3;

  const bf16* agp = hin + (size_t)(m0 + wid*32 + l8)*UNITS + l7*8;
  const int   aoff = (wid*32 + l8)*128 + ((l7 ^ l8) << 4);
  int zcv[4];
  #pragma unroll
  for (int i = 0; i < 4; ++i){
    int lnl = wid*32 + i*8 + l8;
    zcv[i] = ((lnl & 3) << 9) + nu*32 + (lnl >> 2);
  }

  f32x4 acc[4][4];
  #pragma unroll
  for (int i = 0; i < 4; ++i)
    #pragma unroll
    for (int j = 0; j < 4; ++j) acc[i][j] = f32x4{0.f,0.f,0.f,0.f};

  bf16x8 rA[2][4], rB[2][4];
  auto load_set = [&](int s, int k0){
    #pragma unroll
    for (int i = 0; i < 4; ++i){
      rA[s][i] = *reinterpret_cast<const bf16x8*>(agp + (size_t)i*8*UNITS + k0);
      rB[s][i] = *reinterpret_cast<const bf16x8*>(Bt + (size_t)zcv[i]*UNITS + k0 + l7*8);
    }
  };
  auto write_set = [&](int s, int bi){
    char* A = lds + (bi << 14);
    char* B = lds + 32768 + (bi << 14);
    #pragma unroll
    for (int i = 0; i < 4; ++i){
      *reinterpret_cast<bf16x8*>(A + aoff + i*1024) = rA[s][i];
      *reinterpret_cast<bf16x8*>(B + aoff + i*1024) = rB[s][i];
    }
  };
  auto compute = [&](int bi){
    const char* A = lds + (bi << 14);
    const char* B = lds + 32768 + (bi << 14);
    #pragma unroll
    for (int kk = 0; kk < 2; ++kk){
      const int sa = (((kk*4 + kgrp) ^ (l15 & 7)) << 4);
      bf16x8 af[4], bq[4];
      #pragma unroll
      for (int f = 0; f < 4; ++f){
        af[f] = *reinterpret_cast<const bf16x8*>(A + (wm*64 + f*16 + l15)*128 + sa);
        bq[f] = *reinterpret_cast<const bf16x8*>(B + (wn*64 + f*16 + l15)*128 + sa);
      }
      #pragma unroll
      for (int i = 0; i < 4; ++i)
        #pragma unroll
        for (int j = 0; j < 4; ++j)
          acc[i][j] = __builtin_amdgcn_mfma_f32_16x16x32_bf16(af[i], bq[j], acc[i][j], 0, 0, 0);
    }
  };

  bf16x8 xa[4], wq[4];
  if (HAS_X){
    #pragma unroll
    for (int f = 0; f < 4; ++f){
      int row = m0 + wm*64 + f*16 + l15;
      const float* xr = xt + (size_t)row * (TSEQ*FEAT);
      bf16x8 v;
      #pragma unroll
      for (int j = 0; j < 8; ++j) v[j] = (bf16)0.f;
      if (kgrp == 0){
        float4 a = *reinterpret_cast<const float4*>(xr);
        float4 b = *reinterpret_cast<const float4*>(xr + 4);
        v[0]=(bf16)a.x; v[1]=(bf16)a.y; v[2]=(bf16)a.z; v[3]=(bf16)a.w;
        v[4]=(bf16)b.x; v[5]=(bf16)b.y; v[6]=(bf16)b.z; v[7]=(bf16)b.w;
      } else if (kgrp == 1){
        float4 a = *reinterpret_cast<const float4*>(xr + 8);
        v[0]=(bf16)a.x; v[1]=(bf16)a.y; v[2]=(bf16)a.z; v[3]=(bf16)a.w;
      }
      xa[f] = v;
      int lnl = wn*64 + f*16 + l15;
      int zc  = ((lnl & 3) << 9) + nu*32 + (lnl >> 2);
      wq[f] = *reinterpret_cast<const bf16x8*>(Wt + (size_t)zc*32 + kgrp*8);
    }
  }
  const int eu  = tid & 31;
  const int erg = tid >> 5;
  const int cu  = nu*32 + eu;
  float bi_ = bias[0*UNITS + cu];
  float bf_ = bias[1*UNITS + cu];
  float bg_ = bias[2*UNITS + cu];
  float bo_ = bias[3*UNITS + cu];

  load_set(0, 0);
  load_set(1, BK);
  const int rbase = m0 + erg*16;
  float cold[16];
  {
    const float* cp = c + (size_t)rbase*UNITS + cu;
    #pragma unroll
    for (int r = 0; r < 16; ++r) cold[r] = cp[(size_t)r*UNITS];
  }
  write_set(0, 0);
  asm volatile("s_waitcnt lgkmcnt(0)" ::: "memory");
  __builtin_amdgcn_sched_barrier(0);
  __builtin_amdgcn_s_barrier();

  #pragma unroll
  for (int t = 0; t < 8; ++t){
    const int p = t & 1;
    if (t + 2 < 8) load_set(p, (t+2)*BK);
    compute(p);
    if (t < 7){
      write_set(p ^ 1, p ^ 1);
      asm volatile("s_waitcnt lgkmcnt(0)" ::: "memory");
      __builtin_amdgcn_sched_barrier(0);
      __builtin_amdgcn_s_barrier();
    }
  }

  if (HAS_X){
    #pragma unroll
    for (int i = 0; i < 4; ++i)
      #pragma unroll
      for (int j = 0; j < 4; ++j)
        acc[i][j] = __builtin_amdgcn_mfma_f32_16x16x32_bf16(xa[i], wq[j], acc[i][j], 0, 0, 0);
  }

  asm volatile("s_waitcnt lgkmcnt(0)" ::: "memory");
  __builtin_amdgcn_sched_barrier(0);
  __builtin_amdgcn_s_barrier();
  #pragma unroll
  for (int fm = 0; fm < 4; ++fm){
    #pragma unroll
    for (int fn = 0; fn < 4; ++fn){
      int col  = wn*64 + fn*16 + l15;
      int srow = wm*16 + fm*4 + kgrp;
      *reinterpret_cast<f32x4*>(lds + col*512 + ((srow ^ (col & 7)) << 4)) = acc[fm][fn];
    }
  }
  asm volatile("s_waitcnt lgkmcnt(0)" ::: "memory");
  __builtin_amdgcn_sched_barrier(0);
  __builtin_amdgcn_s_barrier();

  #pragma unroll
  for (int q = 0; q < 4; ++q){
    const int s = erg*4 + q;
    f32x4 zi = *reinterpret_cast<const f32x4*>(lds + (eu*4+0)*512 + ((s ^ ((eu*4+0)&7)) << 4));
    f32x4 zf = *reinterpret_cast<const f32x4*>(lds + (eu*4+1)*512 + ((s ^ ((eu*4+1)&7)) << 4));
    f32x4 zg = *reinterpret_cast<const f32x4*>(lds + (eu*4+2)*512 + ((s ^ ((eu*4+2)&7)) << 4));
    f32x4 zo = *reinterpret_cast<const f32x4*>(lds + (eu*4+3)*512 + ((s ^ ((eu*4+3)&7)) << 4));
    #pragma unroll
    for (int rr = 0; rr < 4; ++rr){
      int r = q*4 + rr;
      float iv = sigm_(zi[rr] + bi_);
      float fv = sigm_(zf[rr] + bf_);
      float gv = tanh_(zg[rr] + bg_);
      float ov = sigm_(zo[rr] + bo_);
      float cn = fv*cold[r] + iv*gv;
      size_t idx = (size_t)(rbase + r)*UNITS + cu;
      c[idx]    = cn;
      hout[idx] = (bf16)(ov*tanh_(cn));
    }
  }
}

// ------ pred: out[:, slot, :] = h_slot @ Wd + bd via 16x16x32 MFMA ------
__global__ void pred_all_kernel(const bf16* __restrict__ hbase, size_t slot_stride, int s0,
                                const bf16* __restrict__ Wdt,
                                const float* __restrict__ bd, float* __restrict__ out){
  const int slot = s0 + blockIdx.y;
  const bf16* h  = hbase + (size_t)blockIdx.y * slot_stride;
  const int tid = threadIdx.x, lane = tid & 63, wid = tid >> 6;
  const int l15 = lane & 15, kg = lane >> 4;
  const int r0 = blockIdx.x*64 + wid*16;
  f32x4 acc = f32x4{0.f,0.f,0.f,0.f};
  const bf16* ap = h   + (size_t)(r0 + l15)*UNITS + kg*8;
  const bf16* bp = Wdt + (size_t)l15*UNITS + kg*8;
  #pragma unroll
  for (int ks = 0; ks < 16; ++ks){
    bf16x8 a = *reinterpret_cast<const bf16x8*>(ap + ks*32);
    bf16x8 b = *reinterpret_cast<const bf16x8*>(bp + ks*32);
    acc = __builtin_amdgcn_mfma_f32_16x16x32_bf16(a, b, acc, 0, 0, 0);
  }
  if (l15 < FEAT){
    float bdv = bd[l15];
    #pragma unroll
    for (int r = 0; r < 4; ++r){
      int row = r0 + kg*4 + r;
      out[(size_t)row*(OUTS*FEAT) + slot*FEAT + l15] = acc[r] + bdv;
    }
  }
}

// ------------------------------------------------------------------------
extern "C" void kernel_launch(void* const* d_in, const int* in_sizes, int n_in,
                              void* d_out, int out_size, void* d_ws, size_t ws_size,
                              hipStream_t stream){
  const float* x  = (const float*)d_in[0];
  const float* W  = (const float*)d_in[1];
  const float* U  = (const float*)d_in[2];
  const float* b  = (const float*)d_in[3];
  const float* Wd = (const float*)d_in[4];
  const float* bd = (const float*)d_in[5];
  float* out = (float*)d_out;
  (void)in_sizes; (void)n_in; (void)out_size;
  if (ws_size < WS_NEED) return;
  const bool big = ws_size >= WS_BIG;

  char* ws  = (char*)d_ws;
  bf16* Ut  = (bf16*)(ws + OFF_UT);
  bf16* Uta = (bf16*)(ws + OFF_UTA);
  bf16* Wt  = (bf16*)(ws + OFF_WT);
  float* b2 = (float*)(ws + OFF_B2);
  bf16* Wdt = (bf16*)(ws + OFF_WDT);
  bf16* h0  = (bf16*)(ws + OFF_H0);
  bf16* h1  = (bf16*)(ws + OFF_H1);
  float* c  = (float*)(ws + OFF_C);
  unsigned* bar = (unsigned*)(ws + OFF_BAR);
  bf16* hall= (bf16*)(ws + OFF_HALL);

  hipMemsetAsync(h0, 0, (size_t)NB*UNITS*2, stream);
  hipMemsetAsync(c,  0, (size_t)NB*UNITS*4, stream);
  hipMemsetAsync(bar, 0, 4096, stream);
  prep_u_kernel<<<dim3(32, 8), 256, 0, stream>>>(U, W, Wd, Ut, Uta);
  prep_w_kernel<<<8, 256, 0, stream>>>(W, b, bd, Wd, Wt, b2, Wdt);

  bool done = false;
  if (big){
    const float* xc = x;
    void* args[] = { (void*)&h0, (void*)&h1, (void*)&hall,
                     (void*)&Ut, (void*)&Uta, (void*)&b, (void*)&b2,
                     (void*)&xc, (void*)&Wt, (void*)&bar };
    hipError_t e = hipLaunchCooperativeKernel(
        reinterpret_cast<void*>(lstm_persistent),
        dim3(512), dim3(256), args, 0, stream);
    if (e == hipSuccess){
      pred_all_kernel<<<dim3(NB/64, OUTS), 256, 0, stream>>>(hall, HALL_SL, 0, Wdt, bd, out);
      done = true;
    }
  }

  if (!done){
    if (big){
      bf16* hcur = h0; bf16* hnxt = h1;
      for (int t = 0; t < TSEQ; ++t){
        bf16* dst = (t == TSEQ-1) ? hall : hnxt;
        lstm_step_kernel<1><<<512, 256, 0, stream>>>(hcur, dst, c, Ut, b, x + t*FEAT, Wt);
        hnxt = hcur; hcur = dst;
      }
      for (int s = 1; s < OUTS; ++s)
        lstm_step_kernel<0><<<512, 256, 0, stream>>>(hall + (size_t)(s-1)*HALL_SL,
                                                     hall + (size_t)s*HALL_SL,
                                                     c, Uta, b2, nullptr, nullptr);
      pred_all_kernel<<<dim3(NB/64, OUTS), 256, 0, stream>>>(hall, HALL_SL, 0, Wdt, bd, out);
    } else {
      bf16* hcur = h0; bf16* hnxt = h1;
      for (int t = 0; t < TSEQ; ++t){
        lstm_step_kernel<1><<<512, 256, 0, stream>>>(hcur, hnxt, c, Ut, b, x + t*FEAT, Wt);
        bf16* tmp = hcur; hcur = hnxt; hnxt = tmp;
      }
      pred_all_kernel<<<dim3(NB/64, 1), 256, 0, stream>>>(hcur, 0, 0, Wdt, bd, out);
      for (int s = 1; s < OUTS; ++s){
        lstm_step_kernel<0><<<512, 256, 0, stream>>>(hcur, hnxt, c, Uta, b2, nullptr, nullptr);
        bf16* tmp = hcur; hcur = hnxt; hnxt = tmp;
        pred_all_kernel<<<dim3(NB/64, 1), 256, 0, stream>>>(hcur, 0, s, Wdt, bd, out);
      }
    }
  }
}

// Round 5
// 4738.105 us; speedup vs baseline: 1.2424x; 1.2424x over previous
//
#include <hip/hip_runtime.h>

// FeedBack LSTM: 128 warmup + 31 AR steps, B=4096, UNITS=512, FEAT=12.
//  - AR feedback folded into weights: z = h@(U + Wd@W) + (b + bd@W) (exact).
//  - Per step: [4096,512]@[512,2048] bf16 MFMA GEMM fused with gate math.
//  - R2: reg-staged 2-deep prefetch pipeline, XOR-swizzled LDS, z-through-LDS.
//  - R3: pred via one MFMA kernel over stored h-history (hall ring).
//  - R4: persistent cooperative kernel, c in VGPRs, per-mt-group barriers.
//  - R5: FENCE-FREE coherence. R4's agent acquire/release fences flushed the
//    per-XCD L2 every step (FETCH 20.6 MB/step = Ut refetched by all 8 XCDs).
//    Now h crosses blocks via relaxed agent-scope atomics (sc1 fine-grained
//    coherent, no cache maintenance); ordering = vmcnt(0)+syncthreads before
//    a relaxed flag add. Ut/Uta stay L2-resident; h reads come from L3.

typedef __bf16 bf16;
typedef __attribute__((ext_vector_type(8))) __bf16 bf16x8;
typedef __attribute__((ext_vector_type(4))) float f32x4;

#define NB    4096
#define TSEQ  128
#define FEAT  12
#define UNITS 512
#define NZ    2048
#define OUTS  32
#define NSTEP (TSEQ + OUTS - 1)   // 159

#define BM 128
#define BK 64

// workspace layout (bytes)
#define OFF_UT   ((size_t)0)
#define OFF_UTA  (OFF_UT  + (size_t)NZ*UNITS*2)    // 2 MB
#define OFF_WT   (OFF_UTA + (size_t)NZ*UNITS*2)    // 2 MB
#define OFF_B2   (OFF_WT  + (size_t)NZ*32*2)       // 128 KB
#define OFF_WDT  (OFF_B2  + (size_t)NZ*4)          // 8 KB
#define OFF_H0   (OFF_WDT + (size_t)16*UNITS*2)    // 16 KB
#define OFF_H1   (OFF_H0  + (size_t)NB*UNITS*2)    // 4 MB
#define OFF_C    (OFF_H1  + (size_t)NB*UNITS*2)    // 4 MB
#define OFF_BAR  (OFF_C   + (size_t)NB*UNITS*4)    // +8 MB
#define WS_NEED  (OFF_BAR + 4096)
#define OFF_HALL (WS_NEED)
#define HALL_SL  ((size_t)NB*UNITS)
#define WS_BIG   (OFF_HALL + (size_t)OUTS*NB*UNITS*2)   // +128 MB

__device__ __forceinline__ float fast_exp2(float x){ return __builtin_amdgcn_exp2f(x); }
__device__ __forceinline__ float fast_rcp (float x){ return __builtin_amdgcn_rcpf(x); }
__device__ __forceinline__ float sigm_(float x){ return fast_rcp(1.f + fast_exp2(-1.4426950408889634f*x)); }
__device__ __forceinline__ float tanh_(float x){ return 1.f - 2.f*fast_rcp(1.f + fast_exp2(2.8853900817779268f*x)); }

// coherent (agent-scope, relaxed) h access: per-access sc1, no cache flushes
__device__ __forceinline__ bf16x8 cohload16(const bf16* p){
  union { unsigned long long u[2]; bf16x8 v; } r;
  const unsigned long long* q = (const unsigned long long*)p;
  r.u[0] = __hip_atomic_load(q,     __ATOMIC_RELAXED, __HIP_MEMORY_SCOPE_AGENT);
  r.u[1] = __hip_atomic_load(q + 1, __ATOMIC_RELAXED, __HIP_MEMORY_SCOPE_AGENT);
  return r.v;
}
__device__ __forceinline__ void cohstore_bf16(bf16* p, float v){
  union { bf16 b; unsigned short u; } cv; cv.b = (bf16)v;
  __hip_atomic_store((unsigned short*)p, cv.u, __ATOMIC_RELAXED, __HIP_MEMORY_SCOPE_AGENT);
}

// ---------------- prep: U^T and (U + Wd@W)^T in bf16 --------------------
__global__ void prep_u_kernel(const float* __restrict__ U, const float* __restrict__ W,
                              const float* __restrict__ Wd,
                              bf16* __restrict__ Ut, bf16* __restrict__ Uta){
  __shared__ float su[64][65];
  __shared__ float sa[64][65];
  const int n0 = blockIdx.x * 64;
  const int k0 = blockIdx.y * 64;
  const int tx = threadIdx.x & 63;
  const int rr = threadIdx.x >> 6;
  #pragma unroll 4
  for (int it = 0; it < 16; ++it){
    int k = it*4 + rr;
    float u = U[(size_t)(k0+k)*NZ + n0 + tx];
    float a = u;
    #pragma unroll
    for (int j = 0; j < FEAT; ++j) a += Wd[(k0+k)*FEAT + j] * W[(size_t)j*NZ + n0 + tx];
    su[tx][k] = u;
    sa[tx][k] = a;
  }
  __syncthreads();
  #pragma unroll 4
  for (int it = 0; it < 16; ++it){
    int nl = it*4 + rr;
    Ut [(size_t)(n0+nl)*UNITS + k0 + tx] = (bf16)su[nl][tx];
    Uta[(size_t)(n0+nl)*UNITS + k0 + tx] = (bf16)sa[nl][tx];
  }
}

// ------- prep: W^T (k-padded), b2 = b + bd@W, Wdt = Wd^T (bf16) ---------
__global__ void prep_w_kernel(const float* __restrict__ W, const float* __restrict__ b,
                              const float* __restrict__ bd, const float* __restrict__ Wd,
                              bf16* __restrict__ Wt, float* __restrict__ b2,
                              bf16* __restrict__ Wdt){
  const int n = blockIdx.x*256 + threadIdx.x;
  float acc = b[n];
  #pragma unroll
  for (int j = 0; j < FEAT; ++j){
    float w = W[(size_t)j*NZ + n];
    Wt[(size_t)n*32 + j] = (bf16)w;
    acc += bd[j] * w;
  }
  #pragma unroll
  for (int j = FEAT; j < 32; ++j) Wt[(size_t)n*32 + j] = (bf16)0.f;
  b2[n] = acc;
  if (n < UNITS){
    #pragma unroll
    for (int j = 0; j < FEAT; ++j) Wdt[(size_t)j*UNITS + n] = (bf16)Wd[(size_t)n*FEAT + j];
    #pragma unroll
    for (int j = FEAT; j < 16; ++j) Wdt[(size_t)j*UNITS + n] = (bf16)0.f;
  }
}

// ================= persistent all-steps kernel (cooperative) ============
__launch_bounds__(256, 2)
__global__ void lstm_persistent(bf16* __restrict__ hA,        // zeroed ping [NB,512]
                                bf16* __restrict__ hB,        // pong
                                bf16* __restrict__ hall,      // [OUTS][NB,512]
                                const bf16* __restrict__ Ut,
                                const bf16* __restrict__ Uta,
                                const float* __restrict__ b1, // [2048]
                                const float* __restrict__ b2, // [2048]
                                const float* __restrict__ x,  // [NB,TSEQ,FEAT]
                                const bf16* __restrict__ Wt,  // [2048][32]
                                unsigned* __restrict__ bar)   // [32] zeroed
{
  __shared__ alignas(16) char lds[65536];

  int bid = blockIdx.x;
  bid = (bid & 7) * 64 + (bid >> 3);          // XCD swizzle
  const int mt = bid >> 4;
  const int nu = bid & 15;
  const int m0 = mt * BM;

  const int tid  = threadIdx.x;
  const int lane = tid & 63;
  const int wid  = tid >> 6;
  const int wm   = wid >> 1, wn = wid & 1;
  const int l15  = lane & 15;
  const int kgrp = lane >> 4;
  const int l7   = lane & 7;
  const int l8   = lane >> 3;

  const int    aoff = (wid*32 + l8)*128 + ((l7 ^ l8) << 4);
  const size_t arow = (size_t)(m0 + wid*32 + l8)*UNITS + l7*8;  // + i*8*UNITS + k0
  int zcv[4];
  #pragma unroll
  for (int i = 0; i < 4; ++i){
    int lnl = wid*32 + i*8 + l8;
    zcv[i] = ((lnl & 3) << 9) + nu*32 + (lnl >> 2);
  }

  // hoisted constants: Wt fragments, x row offsets, biases (both phases)
  bf16x8 wq[4];
  int    xrow[4];
  #pragma unroll
  for (int f = 0; f < 4; ++f){
    int lnl = wn*64 + f*16 + l15;
    int zc  = ((lnl & 3) << 9) + nu*32 + (lnl >> 2);
    wq[f] = *reinterpret_cast<const bf16x8*>(Wt + (size_t)zc*32 + kgrp*8);
    xrow[f] = (m0 + wm*64 + f*16 + l15) * (TSEQ*FEAT);
  }
  const int eu  = tid & 31;
  const int erg = tid >> 5;
  const int cu  = nu*32 + eu;
  const float bI1 = b1[0*UNITS+cu], bF1 = b1[1*UNITS+cu], bG1 = b1[2*UNITS+cu], bO1 = b1[3*UNITS+cu];
  const float bI2 = b2[0*UNITS+cu], bF2 = b2[1*UNITS+cu], bG2 = b2[2*UNITS+cu], bO2 = b2[3*UNITS+cu];
  const int rbase = m0 + erg*16;

  float cc[16];
  #pragma unroll
  for (int r = 0; r < 16; ++r) cc[r] = 0.f;

  f32x4 acc[4][4];
  bf16x8 rA[2][4], rB[2][4];

  #pragma unroll 1
  for (int t = 0; t < NSTEP; ++t){
    const bool hasx = (t < TSEQ);
    const bf16* Bt = hasx ? Ut : Uta;
    const bf16* hi = (t < TSEQ) ? ((t & 1) ? hB : hA)
                                : hall + (size_t)(t - TSEQ)*HALL_SL;
    bf16* ho = (t < TSEQ-1) ? ((t & 1) ? hA : hB)
                            : hall + (size_t)(t - (TSEQ-1))*HALL_SL;

    // x fragments for this step (read-only input: safe before the wait)
    bf16x8 xa[4];
    if (hasx){
      #pragma unroll
      for (int f = 0; f < 4; ++f){
        const float* xr = x + xrow[f] + t*FEAT;
        bf16x8 v;
        #pragma unroll
        for (int j = 0; j < 8; ++j) v[j] = (bf16)0.f;
        if (kgrp == 0){
          float4 a = *reinterpret_cast<const float4*>(xr);
          float4 b = *reinterpret_cast<const float4*>(xr + 4);
          v[0]=(bf16)a.x; v[1]=(bf16)a.y; v[2]=(bf16)a.z; v[3]=(bf16)a.w;
          v[4]=(bf16)b.x; v[5]=(bf16)b.y; v[6]=(bf16)b.z; v[7]=(bf16)b.w;
        } else if (kgrp == 1){
          float4 a = *reinterpret_cast<const float4*>(xr + 8);
          v[0]=(bf16)a.x; v[1]=(bf16)a.y; v[2]=(bf16)a.z; v[3]=(bf16)a.w;
        }
        xa[f] = v;
      }
    }

    // ---- wait: producers of this step's h-input (16-block mt-group) ----
    // Relaxed spin, NO fences: h data travels through the coherent point
    // (sc1 loads below can never see stale lines).
    if (t > 0){
      if (tid == 0){
        const unsigned tgt = 16u * (unsigned)t;
        while (__hip_atomic_load(&bar[mt], __ATOMIC_RELAXED, __HIP_MEMORY_SCOPE_AGENT) < tgt)
          __builtin_amdgcn_s_sleep(4);
      }
      __syncthreads();
      __builtin_amdgcn_sched_barrier(0);
    }

    auto load_set = [&](int s, int k0){
      #pragma unroll
      for (int i = 0; i < 4; ++i){
        rA[s][i] = cohload16(hi + arow + (size_t)i*8*UNITS + k0);
        rB[s][i] = *reinterpret_cast<const bf16x8*>(Bt + (size_t)zcv[i]*UNITS + k0 + l7*8);
      }
    };
    auto write_set = [&](int s, int bi){
      char* A = lds + (bi << 14);
      char* B = lds + 32768 + (bi << 14);
      #pragma unroll
      for (int i = 0; i < 4; ++i){
        *reinterpret_cast<bf16x8*>(A + aoff + i*1024) = rA[s][i];
        *reinterpret_cast<bf16x8*>(B + aoff + i*1024) = rB[s][i];
      }
    };
    auto compute = [&](int bi){
      const char* A = lds + (bi << 14);
      const char* B = lds + 32768 + (bi << 14);
      #pragma unroll
      for (int kk = 0; kk < 2; ++kk){
        const int sa = (((kk*4 + kgrp) ^ (l15 & 7)) << 4);
        bf16x8 af[4], bq[4];
        #pragma unroll
        for (int f = 0; f < 4; ++f){
          af[f] = *reinterpret_cast<const bf16x8*>(A + (wm*64 + f*16 + l15)*128 + sa);
          bq[f] = *reinterpret_cast<const bf16x8*>(B + (wn*64 + f*16 + l15)*128 + sa);
        }
        #pragma unroll
        for (int i = 0; i < 4; ++i)
          #pragma unroll
          for (int j = 0; j < 4; ++j)
            acc[i][j] = __builtin_amdgcn_mfma_f32_16x16x32_bf16(af[i], bq[j], acc[i][j], 0, 0, 0);
      }
    };

    #pragma unroll
    for (int i = 0; i < 4; ++i)
      #pragma unroll
      for (int j = 0; j < 4; ++j) acc[i][j] = f32x4{0.f,0.f,0.f,0.f};

    // ---- GEMM: 2-deep reg-staged pipeline over K=512 ----
    load_set(0, 0);
    load_set(1, BK);
    write_set(0, 0);
    asm volatile("s_waitcnt lgkmcnt(0)" ::: "memory");
    __builtin_amdgcn_sched_barrier(0);
    __builtin_amdgcn_s_barrier();

    #pragma unroll
    for (int kt = 0; kt < 8; ++kt){
      const int p = kt & 1;
      if (kt + 2 < 8) load_set(p, (kt+2)*BK);
      compute(p);
      if (kt < 7){
        write_set(p ^ 1, p ^ 1);
        asm volatile("s_waitcnt lgkmcnt(0)" ::: "memory");
        __builtin_amdgcn_sched_barrier(0);
        __builtin_amdgcn_s_barrier();
      }
    }

    if (hasx){
      #pragma unroll
      for (int i = 0; i < 4; ++i)
        #pragma unroll
        for (int j = 0; j < 4; ++j)
          acc[i][j] = __builtin_amdgcn_mfma_f32_16x16x32_bf16(xa[i], wq[j], acc[i][j], 0, 0, 0);
    }

    // ---- z through LDS ----
    asm volatile("s_waitcnt lgkmcnt(0)" ::: "memory");
    __builtin_amdgcn_sched_barrier(0);
    __builtin_amdgcn_s_barrier();

    #pragma unroll
    for (int fm = 0; fm < 4; ++fm){
      #pragma unroll
      for (int fn = 0; fn < 4; ++fn){
        int col  = wn*64 + fn*16 + l15;
        int srow = wm*16 + fm*4 + kgrp;
        *reinterpret_cast<f32x4*>(lds + col*512 + ((srow ^ (col & 7)) << 4)) = acc[fm][fn];
      }
    }
    asm volatile("s_waitcnt lgkmcnt(0)" ::: "memory");
    __builtin_amdgcn_sched_barrier(0);
    __builtin_amdgcn_s_barrier();

    const float bi_ = hasx ? bI1 : bI2;
    const float bf_ = hasx ? bF1 : bF2;
    const float bg_ = hasx ? bG1 : bG2;
    const float bo_ = hasx ? bO1 : bO2;

    #pragma unroll
    for (int q = 0; q < 4; ++q){
      const int s = erg*4 + q;
      f32x4 zi = *reinterpret_cast<const f32x4*>(lds + (eu*4+0)*512 + ((s ^ ((eu*4+0)&7)) << 4));
      f32x4 zf = *reinterpret_cast<const f32x4*>(lds + (eu*4+1)*512 + ((s ^ ((eu*4+1)&7)) << 4));
      f32x4 zg = *reinterpret_cast<const f32x4*>(lds + (eu*4+2)*512 + ((s ^ ((eu*4+2)&7)) << 4));
      f32x4 zo = *reinterpret_cast<const f32x4*>(lds + (eu*4+3)*512 + ((s ^ ((eu*4+3)&7)) << 4));
      #pragma unroll
      for (int rr2 = 0; rr2 < 4; ++rr2){
        int r = q*4 + rr2;
        float iv = sigm_(zi[rr2] + bi_);
        float fv = sigm_(zf[rr2] + bf_);
        float gv = tanh_(zg[rr2] + bg_);
        float ov = sigm_(zo[rr2] + bo_);
        float cn = fv*cc[r] + iv*gv;
        cc[r] = cn;
        cohstore_bf16(ho + (size_t)(rbase + r)*UNITS + cu, ov*tanh_(cn));
      }
    }

    // ---- arrive: all lanes' coherent h-stores ACKed, then relaxed add ----
    if (t < NSTEP - 1){
      asm volatile("s_waitcnt vmcnt(0)" ::: "memory");
      __syncthreads();
      if (tid == 0)
        __hip_atomic_fetch_add(&bar[mt], 1u, __ATOMIC_RELAXED, __HIP_MEMORY_SCOPE_AGENT);
    }
  }
}

// ---------------- per-step kernel (fallback path) -----------------------
template<int HAS_X>
__launch_bounds__(256, 2)
__global__ void lstm_step_kernel(const bf16* __restrict__ hin, bf16* __restrict__ hout,
                                 float* __restrict__ c,
                                 const bf16* __restrict__ Bt,
                                 const float* __restrict__ bias,
                                 const float* __restrict__ xt,
                                 const bf16* __restrict__ Wt)
{
  __shared__ alignas(16) char lds[65536];
  int bid = blockIdx.x;
  bid = (bid & 7) * 64 + (bid >> 3);
  const int mt = bid >> 4;
  const int nu = bid & 15;
  const int m0 = mt * BM;
  const int tid  = threadIdx.x;
  const int lane = tid & 63;
  const int wid  = tid >> 6;
  const int wm   = wid >> 1, wn = wid & 1;
  const int l15  = lane & 15;
  const int kgrp = lane >> 4;
  const int l7   = lane & 7;
  const int l8   = lane >> 3;

  const bf16* agp = hin + (size_t)(m0 + wid*32 + l8)*UNITS + l7*8;
  const int   aoff = (wid*32 + l8)*128 + ((l7 ^ l8) << 4);
  int zcv[4];
  #pragma unroll
  for (int i = 0; i < 4; ++i){
    int lnl = wid*32 + i*8 + l8;
    zcv[i] = ((lnl & 3) << 9) + nu*32 + (lnl >> 2);
  }

  f32x4 acc[4][4];
  #pragma unroll
  for (int i = 0; i < 4; ++i)
    #pragma unroll
    for (int j = 0; j < 4; ++j) acc[i][j] = f32x4{0.f,0.f,0.f,0.f};

  bf16x8 rA[2][4], rB[2][4];
  auto load_set = [&](int s, int k0){
    #pragma unroll
    for (int i = 0; i < 4; ++i){
      rA[s][i] = *reinterpret_cast<const bf16x8*>(agp + (size_t)i*8*UNITS + k0);
      rB[s][i] = *reinterpret_cast<const bf16x8*>(Bt + (size_t)zcv[i]*UNITS + k0 + l7*8);
    }
  };
  auto write_set = [&](int s, int bi){
    char* A = lds + (bi << 14);
    char* B = lds + 32768 + (bi << 14);
    #pragma unroll
    for (int i = 0; i < 4; ++i){
      *reinterpret_cast<bf16x8*>(A + aoff + i*1024) = rA[s][i];
      *reinterpret_cast<bf16x8*>(B + aoff + i*1024) = rB[s][i];
    }
  };
  auto compute = [&](int bi){
    const char* A = lds + (bi << 14);
    const char* B = lds + 32768 + (bi << 14);
    #pragma unroll
    for (int kk = 0; kk < 2; ++kk){
      const int sa = (((kk*4 + kgrp) ^ (l15 & 7)) << 4);
      bf16x8 af[4], bq[4];
      #pragma unroll
      for (int f = 0; f < 4; ++f){
        af[f] = *reinterpret_cast<const bf16x8*>(A + (wm*64 + f*16 + l15)*128 + sa);
        bq[f] = *reinterpret_cast<const bf16x8*>(B + (wn*64 + f*16 + l15)*128 + sa);
      }
      #pragma unroll
      for (int i = 0; i < 4; ++i)
        #pragma unroll
        for (int j = 0; j < 4; ++j)
          acc[i][j] = __builtin_amdgcn_mfma_f32_16x16x32_bf16(af[i], bq[j], acc[i][j], 0, 0, 0);
    }
  };

  bf16x8 xa[4], wq[4];
  if (HAS_X){
    #pragma unroll
    for (int f = 0; f < 4; ++f){
      int row = m0 + wm*64 + f*16 + l15;
      const float* xr = xt + (size_t)row * (TSEQ*FEAT);
      bf16x8 v;
      #pragma unroll
      for (int j = 0; j < 8; ++j) v[j] = (bf16)0.f;
      if (kgrp == 0){
        float4 a = *reinterpret_cast<const float4*>(xr);
        float4 b = *reinterpret_cast<const float4*>(xr + 4);
        v[0]=(bf16)a.x; v[1]=(bf16)a.y; v[2]=(bf16)a.z; v[3]=(bf16)a.w;
        v[4]=(bf16)b.x; v[5]=(bf16)b.y; v[6]=(bf16)b.z; v[7]=(bf16)b.w;
      } else if (kgrp == 1){
        float4 a = *reinterpret_cast<const float4*>(xr + 8);
        v[0]=(bf16)a.x; v[1]=(bf16)a.y; v[2]=(bf16)a.z; v[3]=(bf16)a.w;
      }
      xa[f] = v;
      int lnl = wn*64 + f*16 + l15;
      int zc  = ((lnl & 3) << 9) + nu*32 + (lnl >> 2);
      wq[f] = *reinterpret_cast<const bf16x8*>(Wt + (size_t)zc*32 + kgrp*8);
    }
  }
  const int eu  = tid & 31;
  const int erg = tid >> 5;
  const int cu  = nu*32 + eu;
  float bi_ = bias[0*UNITS + cu];
  float bf_ = bias[1*UNITS + cu];
  float bg_ = bias[2*UNITS + cu];
  float bo_ = bias[3*UNITS + cu];

  load_set(0, 0);
  load_set(1, BK);
  const int rbase = m0 + erg*16;
  float cold[16];
  {
    const float* cp = c + (size_t)rbase*UNITS + cu;
    #pragma unroll
    for (int r = 0; r < 16; ++r) cold[r] = cp[(size_t)r*UNITS];
  }
  write_set(0, 0);
  asm volatile("s_waitcnt lgkmcnt(0)" ::: "memory");
  __builtin_amdgcn_sched_barrier(0);
  __builtin_amdgcn_s_barrier();

  #pragma unroll
  for (int t = 0; t < 8; ++t){
    const int p = t & 1;
    if (t + 2 < 8) load_set(p, (t+2)*BK);
    compute(p);
    if (t < 7){
      write_set(p ^ 1, p ^ 1);
      asm volatile("s_waitcnt lgkmcnt(0)" ::: "memory");
      __builtin_amdgcn_sched_barrier(0);
      __builtin_amdgcn_s_barrier();
    }
  }

  if (HAS_X){
    #pragma unroll
    for (int i = 0; i < 4; ++i)
      #pragma unroll
      for (int j = 0; j < 4; ++j)
        acc[i][j] = __builtin_amdgcn_mfma_f32_16x16x32_bf16(xa[i], wq[j], acc[i][j], 0, 0, 0);
  }

  asm volatile("s_waitcnt lgkmcnt(0)" ::: "memory");
  __builtin_amdgcn_sched_barrier(0);
  __builtin_amdgcn_s_barrier();
  #pragma unroll
  for (int fm = 0; fm < 4; ++fm){
    #pragma unroll
    for (int fn = 0; fn < 4; ++fn){
      int col  = wn*64 + fn*16 + l15;
      int srow = wm*16 + fm*4 + kgrp;
      *reinterpret_cast<f32x4*>(lds + col*512 + ((srow ^ (col & 7)) << 4)) = acc[fm][fn];
    }
  }
  asm volatile("s_waitcnt lgkmcnt(0)" ::: "memory");
  __builtin_amdgcn_sched_barrier(0);
  __builtin_amdgcn_s_barrier();

  #pragma unroll
  for (int q = 0; q < 4; ++q){
    const int s = erg*4 + q;
    f32x4 zi = *reinterpret_cast<const f32x4*>(lds + (eu*4+0)*512 + ((s ^ ((eu*4+0)&7)) << 4));
    f32x4 zf = *reinterpret_cast<const f32x4*>(lds + (eu*4+1)*512 + ((s ^ ((eu*4+1)&7)) << 4));
    f32x4 zg = *reinterpret_cast<const f32x4*>(lds + (eu*4+2)*512 + ((s ^ ((eu*4+2)&7)) << 4));
    f32x4 zo = *reinterpret_cast<const f32x4*>(lds + (eu*4+3)*512 + ((s ^ ((eu*4+3)&7)) << 4));
    #pragma unroll
    for (int rr = 0; rr < 4; ++rr){
      int r = q*4 + rr;
      float iv = sigm_(zi[rr] + bi_);
      float fv = sigm_(zf[rr] + bf_);
      float gv = tanh_(zg[rr] + bg_);
      float ov = sigm_(zo[rr] + bo_);
      float cn = fv*cold[r] + iv*gv;
      size_t idx = (size_t)(rbase + r)*UNITS + cu;
      c[idx]    = cn;
      hout[idx] = (bf16)(ov*tanh_(cn));
    }
  }
}

// ------ pred: out[:, slot, :] = h_slot @ Wd + bd via 16x16x32 MFMA ------
__global__ void pred_all_kernel(const bf16* __restrict__ hbase, size_t slot_stride, int s0,
                                const bf16* __restrict__ Wdt,
                                const float* __restrict__ bd, float* __restrict__ out){
  const int slot = s0 + blockIdx.y;
  const bf16* h  = hbase + (size_t)blockIdx.y * slot_stride;
  const int tid = threadIdx.x, lane = tid & 63, wid = tid >> 6;
  const int l15 = lane & 15, kg = lane >> 4;
  const int r0 = blockIdx.x*64 + wid*16;
  f32x4 acc = f32x4{0.f,0.f,0.f,0.f};
  const bf16* ap = h   + (size_t)(r0 + l15)*UNITS + kg*8;
  const bf16* bp = Wdt + (size_t)l15*UNITS + kg*8;
  #pragma unroll
  for (int ks = 0; ks < 16; ++ks){
    bf16x8 a = *reinterpret_cast<const bf16x8*>(ap + ks*32);
    bf16x8 b = *reinterpret_cast<const bf16x8*>(bp + ks*32);
    acc = __builtin_amdgcn_mfma_f32_16x16x32_bf16(a, b, acc, 0, 0, 0);
  }
  if (l15 < FEAT){
    float bdv = bd[l15];
    #pragma unroll
    for (int r = 0; r < 4; ++r){
      int row = r0 + kg*4 + r;
      out[(size_t)row*(OUTS*FEAT) + slot*FEAT + l15] = acc[r] + bdv;
    }
  }
}

// ------------------------------------------------------------------------
extern "C" void kernel_launch(void* const* d_in, const int* in_sizes, int n_in,
                              void* d_out, int out_size, void* d_ws, size_t ws_size,
                              hipStream_t stream){
  const float* x  = (const float*)d_in[0];
  const float* W  = (const float*)d_in[1];
  const float* U  = (const float*)d_in[2];
  const float* b  = (const float*)d_in[3];
  const float* Wd = (const float*)d_in[4];
  const float* bd = (const float*)d_in[5];
  float* out = (float*)d_out;
  (void)in_sizes; (void)n_in; (void)out_size;
  if (ws_size < WS_NEED) return;
  const bool big = ws_size >= WS_BIG;

  char* ws  = (char*)d_ws;
  bf16* Ut  = (bf16*)(ws + OFF_UT);
  bf16* Uta = (bf16*)(ws + OFF_UTA);
  bf16* Wt  = (bf16*)(ws + OFF_WT);
  float* b2 = (float*)(ws + OFF_B2);
  bf16* Wdt = (bf16*)(ws + OFF_WDT);
  bf16* h0  = (bf16*)(ws + OFF_H0);
  bf16* h1  = (bf16*)(ws + OFF_H1);
  float* c  = (float*)(ws + OFF_C);
  unsigned* bar = (unsigned*)(ws + OFF_BAR);
  bf16* hall= (bf16*)(ws + OFF_HALL);

  hipMemsetAsync(h0, 0, (size_t)NB*UNITS*2, stream);
  hipMemsetAsync(c,  0, (size_t)NB*UNITS*4, stream);
  hipMemsetAsync(bar, 0, 4096, stream);
  prep_u_kernel<<<dim3(32, 8), 256, 0, stream>>>(U, W, Wd, Ut, Uta);
  prep_w_kernel<<<8, 256, 0, stream>>>(W, b, bd, Wd, Wt, b2, Wdt);

  bool done = false;
  if (big){
    const float* xc = x;
    void* args[] = { (void*)&h0, (void*)&h1, (void*)&hall,
                     (void*)&Ut, (void*)&Uta, (void*)&b, (void*)&b2,
                     (void*)&xc, (void*)&Wt, (void*)&bar };
    hipError_t e = hipLaunchCooperativeKernel(
        reinterpret_cast<void*>(lstm_persistent),
        dim3(512), dim3(256), args, 0, stream);
    if (e == hipSuccess){
      pred_all_kernel<<<dim3(NB/64, OUTS), 256, 0, stream>>>(hall, HALL_SL, 0, Wdt, bd, out);
      done = true;
    }
  }

  if (!done){
    if (big){
      bf16* hcur = h0; bf16* hnxt = h1;
      for (int t = 0; t < TSEQ; ++t){
        bf16* dst = (t == TSEQ-1) ? hall : hnxt;
        lstm_step_kernel<1><<<512, 256, 0, stream>>>(hcur, dst, c, Ut, b, x + t*FEAT, Wt);
        hnxt = hcur; hcur = dst;
      }
      for (int s = 1; s < OUTS; ++s)
        lstm_step_kernel<0><<<512, 256, 0, stream>>>(hall + (size_t)(s-1)*HALL_SL,
                                                     hall + (size_t)s*HALL_SL,
                                                     c, Uta, b2, nullptr, nullptr);
      pred_all_kernel<<<dim3(NB/64, OUTS), 256, 0, stream>>>(hall, HALL_SL, 0, Wdt, bd, out);
    } else {
      bf16* hcur = h0; bf16* hnxt = h1;
      for (int t = 0; t < TSEQ; ++t){
        lstm_step_kernel<1><<<512, 256, 0, stream>>>(hcur, hnxt, c, Ut, b, x + t*FEAT, Wt);
        bf16* tmp = hcur; hcur = hnxt; hnxt = tmp;
      }
      pred_all_kernel<<<dim3(NB/64, 1), 256, 0, stream>>>(hcur, 0, 0, Wdt, bd, out);
      for (int s = 1; s < OUTS; ++s){
        lstm_step_kernel<0><<<512, 256, 0, stream>>>(hcur, hnxt, c, Uta, b2, nullptr, nullptr);
        bf16* tmp = hcur; hcur = hnxt; hnxt = tmp;
        pred_all_kernel<<<dim3(NB/64, 1), 256, 0, stream>>>(hcur, 0, s, Wdt, bd, out);
      }
    }
  }
}

// Round 7
// 3157.257 us; speedup vs baseline: 1.8644x; 1.5007x over previous
//
#include <hip/hip_runtime.h>

// FeedBack LSTM: 128 warmup + 31 AR steps, B=4096, UNITS=512, FEAT=12.
//  - AR feedback folded into weights: z = h@(U + Wd@W) + (b + bd@W) (exact).
//  - Per step: [4096,512]@[512,2048] bf16 MFMA GEMM fused with gate math.
//  - R2: reg-staged 2-deep prefetch pipeline, XOR-swizzled LDS, z-through-LDS.
//  - R3: pred via one MFMA kernel over stored h-history (hall ring).
//  - R4/R5: persistent cooperative kernel — REVERTED (lost to plain launches).
//  - R6: B-operand direct global->VGPR from fragment-major packed U^T
//    (1 KB contiguous per wave-fragment, 2-deep prefetch); LDS stages A only.
//  - R7: fix R6's packed-layout stride bug (frag*4096 -> frag*1024: 8 MB
//    written into a 2 MB buffer, clobbering h/c). Dense layout:
//    byte = frag*1024 + kgrp*256 + l15*16 + e*2, total exactly 2 MB.

typedef __bf16 bf16;
typedef __attribute__((ext_vector_type(8))) __bf16 bf16x8;
typedef __attribute__((ext_vector_type(4))) float f32x4;

#define NB    4096
#define TSEQ  128
#define FEAT  12
#define UNITS 512
#define NZ    2048
#define OUTS  32

#define BM 128
#define BK 64

// workspace layout (bytes)
#define OFF_UT   ((size_t)0)
#define OFF_UTA  (OFF_UT  + (size_t)NZ*UNITS*2)    // 2 MB  (packed U^T)
#define OFF_WT   (OFF_UTA + (size_t)NZ*UNITS*2)    // 2 MB  (packed (U+WdW)^T)
#define OFF_B2   (OFF_WT  + (size_t)NZ*32*2)       // 128 KB
#define OFF_WDT  (OFF_B2  + (size_t)NZ*4)          // 8 KB
#define OFF_H0   (OFF_WDT + (size_t)16*UNITS*2)    // 16 KB
#define OFF_H1   (OFF_H0  + (size_t)NB*UNITS*2)    // 4 MB
#define OFF_C    (OFF_H1  + (size_t)NB*UNITS*2)    // 4 MB
#define WS_NEED  (OFF_C   + (size_t)NB*UNITS*4)    // +8 MB
#define OFF_HALL (WS_NEED)
#define HALL_SL  ((size_t)NB*UNITS)
#define WS_BIG   (OFF_HALL + (size_t)OUTS*NB*UNITS*2)   // +128 MB

__device__ __forceinline__ float fast_exp2(float x){ return __builtin_amdgcn_exp2f(x); }
__device__ __forceinline__ float fast_rcp (float x){ return __builtin_amdgcn_rcpf(x); }
__device__ __forceinline__ float sigm_(float x){ return fast_rcp(1.f + fast_exp2(-1.4426950408889634f*x)); }
__device__ __forceinline__ float tanh_(float x){ return 1.f - 2.f*fast_rcp(1.f + fast_exp2(2.8853900817779268f*x)); }

// ---- fragment-major packed B layout (DENSE, 2 MB total) ----------------
//   lnl = wn*64+f*16+l15 (block-local col), n = gate<<9 | nu*32 + lnl>>2,
//   k = it*64 + kk*32 + kgrp*8 + e
//   frag = (((nu*2+wn)*4+f)*8 + it)*2 + kk          (0..2047)
//   byte = frag*1024 + kgrp*256 + l15*16 + e*2      (< 2 MB)
__device__ __forceinline__ size_t bp_off(int n, int k){
  int g  = n >> 9;             // gate
  int uc = n & 511;            // unit
  int nu = uc >> 5, uo = uc & 31;
  int lnl = uo*4 + g;
  int wn = lnl >> 6, f = (lnl >> 4) & 3, l15 = lnl & 15;
  int it = k >> 6, kk = (k >> 5) & 1, kgrp = (k >> 3) & 3, e = k & 7;
  int frag = (((nu*2 + wn)*4 + f)*8 + it)*2 + kk;
  return (size_t)frag*1024 + kgrp*256 + l15*16 + e*2;
}

// ---------------- prep: packed U^T and packed (U + Wd@W)^T --------------
__global__ void prep_u_kernel(const float* __restrict__ U, const float* __restrict__ W,
                              const float* __restrict__ Wd,
                              bf16* __restrict__ Utp, bf16* __restrict__ Utap){
  __shared__ float su[64][65];
  __shared__ float sa[64][65];
  const int n0 = blockIdx.x * 64;          // 32 blocks over N=2048
  const int k0 = blockIdx.y * 64;          // 8 blocks over K=512
  const int tx = threadIdx.x & 63;
  const int rr = threadIdx.x >> 6;
  #pragma unroll 4
  for (int it = 0; it < 16; ++it){
    int k = it*4 + rr;
    float u = U[(size_t)(k0+k)*NZ + n0 + tx];
    float a = u;
    #pragma unroll
    for (int j = 0; j < FEAT; ++j) a += Wd[(k0+k)*FEAT + j] * W[(size_t)j*NZ + n0 + tx];
    su[tx][k] = u;   // [n-local][k-local]
    sa[tx][k] = a;
  }
  __syncthreads();
  // write packed: thread quadrant q: bit0 -> array, bit1 -> k-half
  const int nl = threadIdx.x & 63;
  const int q  = threadIdx.x >> 6;
  const float (*src)[65] = (q & 1) ? sa : su;
  char* dst = (char*)((q & 1) ? Utap : Utp);
  const int kh = (q >> 1) * 32;
  #pragma unroll
  for (int kc = 0; kc < 32; kc += 8){
    bf16x8 v;
    #pragma unroll
    for (int e = 0; e < 8; ++e) v[e] = (bf16)src[nl][kh + kc + e];
    *reinterpret_cast<bf16x8*>(dst + bp_off(n0 + nl, k0 + kh + kc)) = v;
  }
}

// ------- prep: W^T (k-padded), b2 = b + bd@W, Wdt = Wd^T (bf16) ---------
__global__ void prep_w_kernel(const float* __restrict__ W, const float* __restrict__ b,
                              const float* __restrict__ bd, const float* __restrict__ Wd,
                              bf16* __restrict__ Wt, float* __restrict__ b2,
                              bf16* __restrict__ Wdt){
  const int n = blockIdx.x*256 + threadIdx.x;
  float acc = b[n];
  #pragma unroll
  for (int j = 0; j < FEAT; ++j){
    float w = W[(size_t)j*NZ + n];
    Wt[(size_t)n*32 + j] = (bf16)w;
    acc += bd[j] * w;
  }
  #pragma unroll
  for (int j = FEAT; j < 32; ++j) Wt[(size_t)n*32 + j] = (bf16)0.f;
  b2[n] = acc;
  if (n < UNITS){
    #pragma unroll
    for (int j = 0; j < FEAT; ++j) Wdt[(size_t)j*UNITS + n] = (bf16)Wd[(size_t)n*FEAT + j];
    #pragma unroll
    for (int j = FEAT; j < 16; ++j) Wdt[(size_t)j*UNITS + n] = (bf16)0.f;
  }
}

// ---------------- one LSTM step (fused GEMM + gates) --------------------
// grid 512 = 32 m-tiles x 16 unit-tiles, 256 threads (4 waves).
// A (h) staged in LDS (2-deep reg pipeline); B direct from packed global.
template<int HAS_X>
__launch_bounds__(256, 2)
__global__ void lstm_step_kernel(const bf16* __restrict__ hin, bf16* __restrict__ hout,
                                 float* __restrict__ c,
                                 const bf16* __restrict__ Bp,    // packed 2 MB
                                 const float* __restrict__ bias, // [2048]
                                 const float* __restrict__ xt,   // x + t*FEAT
                                 const bf16* __restrict__ Wt)    // [2048][32]
{
  __shared__ alignas(16) char lds[65536];
  // A0 @0, A1 @16K (128 rows x 128B each); z-tile reuses all 64KB.

  int bid = blockIdx.x;
  bid = (bid & 7) * 64 + (bid >> 3);          // XCD swizzle
  const int mt = bid >> 4;
  const int nu = bid & 15;
  const int m0 = mt * BM;

  const int tid  = threadIdx.x;
  const int lane = tid & 63;
  const int wid  = tid >> 6;
  const int wm   = wid >> 1, wn = wid & 1;
  const int l15  = lane & 15;
  const int kgrp = lane >> 4;
  const int l7   = lane & 7;
  const int l8   = lane >> 3;

  // A staging addresses
  const bf16* agp = hin + (size_t)(m0 + wid*32 + l8)*UNITS + l7*8;
  const int   aoff = (wid*32 + l8)*128 + ((l7 ^ l8) << 4);

  // B packed base: + f*16384 + it*2048 + kk*1024 per fragment
  const char* bp = (const char*)Bp + (size_t)(nu*2 + wn)*65536 + kgrp*256 + l15*16;

  f32x4 acc[4][4];
  #pragma unroll
  for (int i = 0; i < 4; ++i)
    #pragma unroll
    for (int j = 0; j < 4; ++j) acc[i][j] = f32x4{0.f,0.f,0.f,0.f};

  bf16x8 rA[2][4];
  bf16x8 rB[2][8];   // [set][f*2+kk]

  auto loadA_set = [&](int s, int k0){
    #pragma unroll
    for (int i = 0; i < 4; ++i)
      rA[s][i] = *reinterpret_cast<const bf16x8*>(agp + (size_t)i*8*UNITS + k0);
  };
  auto loadB_set = [&](int s, int it){
    #pragma unroll
    for (int f = 0; f < 4; ++f)
      #pragma unroll
      for (int kk = 0; kk < 2; ++kk)
        rB[s][f*2+kk] = *reinterpret_cast<const bf16x8*>(bp + f*16384 + it*2048 + kk*1024);
  };
  auto writeA_set = [&](int s, int bi){
    char* A = lds + (bi << 14);
    #pragma unroll
    for (int i = 0; i < 4; ++i)
      *reinterpret_cast<bf16x8*>(A + aoff + i*1024) = rA[s][i];
  };
  auto compute = [&](int bi, int s){
    const char* A = lds + (bi << 14);
    #pragma unroll
    for (int kk = 0; kk < 2; ++kk){
      const int sa = (((kk*4 + kgrp) ^ (l15 & 7)) << 4);
      bf16x8 af[4];
      #pragma unroll
      for (int f = 0; f < 4; ++f)
        af[f] = *reinterpret_cast<const bf16x8*>(A + (wm*64 + f*16 + l15)*128 + sa);
      #pragma unroll
      for (int i = 0; i < 4; ++i)
        #pragma unroll
        for (int j = 0; j < 4; ++j)
          acc[i][j] = __builtin_amdgcn_mfma_f32_16x16x32_bf16(af[i], rB[s][j*2+kk], acc[i][j], 0, 0, 0);
    }
  };

  // hoisted x / Wt fragments (HAS_X) and epilogue biases
  bf16x8 xa[4], wq[4];
  if (HAS_X){
    #pragma unroll
    for (int f = 0; f < 4; ++f){
      int row = m0 + wm*64 + f*16 + l15;
      const float* xr = xt + (size_t)row * (TSEQ*FEAT);
      bf16x8 v;
      #pragma unroll
      for (int j = 0; j < 8; ++j) v[j] = (bf16)0.f;
      if (kgrp == 0){
        float4 a = *reinterpret_cast<const float4*>(xr);
        float4 b = *reinterpret_cast<const float4*>(xr + 4);
        v[0]=(bf16)a.x; v[1]=(bf16)a.y; v[2]=(bf16)a.z; v[3]=(bf16)a.w;
        v[4]=(bf16)b.x; v[5]=(bf16)b.y; v[6]=(bf16)b.z; v[7]=(bf16)b.w;
      } else if (kgrp == 1){
        float4 a = *reinterpret_cast<const float4*>(xr + 8);
        v[0]=(bf16)a.x; v[1]=(bf16)a.y; v[2]=(bf16)a.z; v[3]=(bf16)a.w;
      }
      xa[f] = v;
      int lnl = wn*64 + f*16 + l15;
      int zc  = ((lnl & 3) << 9) + nu*32 + (lnl >> 2);
      wq[f] = *reinterpret_cast<const bf16x8*>(Wt + (size_t)zc*32 + kgrp*8);
    }
  }
  const int eu  = tid & 31;
  const int erg = tid >> 5;
  const int cu  = nu*32 + eu;
  float bi_ = bias[0*UNITS + cu];
  float bf_ = bias[1*UNITS + cu];
  float bg_ = bias[2*UNITS + cu];
  float bo_ = bias[3*UNITS + cu];

  // ---- pipeline prologue ----
  loadA_set(0, 0);
  loadB_set(0, 0);
  loadA_set(1, BK);
  loadB_set(1, 1);

  // hoisted c-reads: issue now, consumed (counted-vmcnt) in epilogue
  const int rbase = m0 + erg*16;
  float cold[16];
  {
    const float* cp = c + (size_t)rbase*UNITS + cu;
    #pragma unroll
    for (int r = 0; r < 16; ++r) cold[r] = cp[(size_t)r*UNITS];
  }

  writeA_set(0, 0);
  asm volatile("s_waitcnt lgkmcnt(0)" ::: "memory");
  __builtin_amdgcn_sched_barrier(0);
  __builtin_amdgcn_s_barrier();

  // ---- main loop: compute t; prefetch A(t+2) before, B(t+2) after -----
  #pragma unroll
  for (int t = 0; t < 8; ++t){
    const int p = t & 1;
    if (t + 2 < 8) loadA_set(p, (t+2)*BK);
    compute(p, p);
    if (t + 2 < 8) loadB_set(p, t+2);        // rB[p] free after compute
    if (t < 7){
      writeA_set(p ^ 1, p ^ 1);
      asm volatile("s_waitcnt lgkmcnt(0)" ::: "memory");
      __builtin_amdgcn_sched_barrier(0);
      __builtin_amdgcn_s_barrier();
    }
  }

  if (HAS_X){
    #pragma unroll
    for (int i = 0; i < 4; ++i)
      #pragma unroll
      for (int j = 0; j < 4; ++j)
        acc[i][j] = __builtin_amdgcn_mfma_f32_16x16x32_bf16(xa[i], wq[j], acc[i][j], 0, 0, 0);
  }

  // ---- z through LDS: store transposed+swizzled, re-read all-lane ----
  asm volatile("s_waitcnt lgkmcnt(0)" ::: "memory");
  __builtin_amdgcn_sched_barrier(0);
  __builtin_amdgcn_s_barrier();

  #pragma unroll
  for (int fm = 0; fm < 4; ++fm){
    #pragma unroll
    for (int fn = 0; fn < 4; ++fn){
      int col  = wn*64 + fn*16 + l15;
      int srow = wm*16 + fm*4 + kgrp;
      *reinterpret_cast<f32x4*>(lds + col*512 + ((srow ^ (col & 7)) << 4)) = acc[fm][fn];
    }
  }
  asm volatile("s_waitcnt lgkmcnt(0)" ::: "memory");
  __builtin_amdgcn_sched_barrier(0);
  __builtin_amdgcn_s_barrier();

  #pragma unroll
  for (int q = 0; q < 4; ++q){
    const int s = erg*4 + q;
    f32x4 zi = *reinterpret_cast<const f32x4*>(lds + (eu*4+0)*512 + ((s ^ ((eu*4+0)&7)) << 4));
    f32x4 zf = *reinterpret_cast<const f32x4*>(lds + (eu*4+1)*512 + ((s ^ ((eu*4+1)&7)) << 4));
    f32x4 zg = *reinterpret_cast<const f32x4*>(lds + (eu*4+2)*512 + ((s ^ ((eu*4+2)&7)) << 4));
    f32x4 zo = *reinterpret_cast<const f32x4*>(lds + (eu*4+3)*512 + ((s ^ ((eu*4+3)&7)) << 4));
    #pragma unroll
    for (int rr = 0; rr < 4; ++rr){
      int r = q*4 + rr;
      float iv = sigm_(zi[rr] + bi_);
      float fv = sigm_(zf[rr] + bf_);
      float gv = tanh_(zg[rr] + bg_);
      float ov = sigm_(zo[rr] + bo_);
      float cn = fv*cold[r] + iv*gv;
      size_t idx = (size_t)(rbase + r)*UNITS + cu;
      c[idx]    = cn;
      hout[idx] = (bf16)(ov*tanh_(cn));
    }
  }
}

// ------ pred: out[:, slot, :] = h_slot @ Wd + bd via 16x16x32 MFMA ------
__global__ void pred_all_kernel(const bf16* __restrict__ hbase, size_t slot_stride, int s0,
                                const bf16* __restrict__ Wdt,
                                const float* __restrict__ bd, float* __restrict__ out){
  const int slot = s0 + blockIdx.y;
  const bf16* h  = hbase + (size_t)blockIdx.y * slot_stride;
  const int tid = threadIdx.x, lane = tid & 63, wid = tid >> 6;
  const int l15 = lane & 15, kg = lane >> 4;
  const int r0 = blockIdx.x*64 + wid*16;
  f32x4 acc = f32x4{0.f,0.f,0.f,0.f};
  const bf16* ap = h   + (size_t)(r0 + l15)*UNITS + kg*8;
  const bf16* bp = Wdt + (size_t)l15*UNITS + kg*8;
  #pragma unroll
  for (int ks = 0; ks < 16; ++ks){
    bf16x8 a = *reinterpret_cast<const bf16x8*>(ap + ks*32);
    bf16x8 b = *reinterpret_cast<const bf16x8*>(bp + ks*32);
    acc = __builtin_amdgcn_mfma_f32_16x16x32_bf16(a, b, acc, 0, 0, 0);
  }
  if (l15 < FEAT){
    float bdv = bd[l15];
    #pragma unroll
    for (int r = 0; r < 4; ++r){
      int row = r0 + kg*4 + r;
      out[(size_t)row*(OUTS*FEAT) + slot*FEAT + l15] = acc[r] + bdv;
    }
  }
}

// ------------------------------------------------------------------------
extern "C" void kernel_launch(void* const* d_in, const int* in_sizes, int n_in,
                              void* d_out, int out_size, void* d_ws, size_t ws_size,
                              hipStream_t stream){
  const float* x  = (const float*)d_in[0];
  const float* W  = (const float*)d_in[1];
  const float* U  = (const float*)d_in[2];
  const float* b  = (const float*)d_in[3];
  const float* Wd = (const float*)d_in[4];
  const float* bd = (const float*)d_in[5];
  float* out = (float*)d_out;
  (void)in_sizes; (void)n_in; (void)out_size;
  if (ws_size < WS_NEED) return;
  const bool big = ws_size >= WS_BIG;

  char* ws  = (char*)d_ws;
  bf16* Utp = (bf16*)(ws + OFF_UT);
  bf16* Utap= (bf16*)(ws + OFF_UTA);
  bf16* Wt  = (bf16*)(ws + OFF_WT);
  float* b2 = (float*)(ws + OFF_B2);
  bf16* Wdt = (bf16*)(ws + OFF_WDT);
  bf16* h0  = (bf16*)(ws + OFF_H0);
  bf16* h1  = (bf16*)(ws + OFF_H1);
  float* c  = (float*)(ws + OFF_C);
  bf16* hall= (bf16*)(ws + OFF_HALL);

  hipMemsetAsync(h0, 0, (size_t)NB*UNITS*2, stream);
  hipMemsetAsync(c,  0, (size_t)NB*UNITS*4, stream);
  prep_u_kernel<<<dim3(32, 8), 256, 0, stream>>>(U, W, Wd, Utp, Utap);
  prep_w_kernel<<<8, 256, 0, stream>>>(W, b, bd, Wd, Wt, b2, Wdt);

  if (big){
    bf16* hcur = h0; bf16* hnxt = h1;
    for (int t = 0; t < TSEQ; ++t){
      bf16* dst = (t == TSEQ-1) ? hall : hnxt;
      lstm_step_kernel<1><<<512, 256, 0, stream>>>(hcur, dst, c, Utp, b, x + t*FEAT, Wt);
      hnxt = hcur; hcur = dst;
    }
    for (int s = 1; s < OUTS; ++s)
      lstm_step_kernel<0><<<512, 256, 0, stream>>>(hall + (size_t)(s-1)*HALL_SL,
                                                   hall + (size_t)s*HALL_SL,
                                                   c, Utap, b2, nullptr, nullptr);
    pred_all_kernel<<<dim3(NB/64, OUTS), 256, 0, stream>>>(hall, HALL_SL, 0, Wdt, bd, out);
  } else {
    bf16* hcur = h0; bf16* hnxt = h1;
    for (int t = 0; t < TSEQ; ++t){
      lstm_step_kernel<1><<<512, 256, 0, stream>>>(hcur, hnxt, c, Utp, b, x + t*FEAT, Wt);
      bf16* tmp = hcur; hcur = hnxt; hnxt = tmp;
    }
    pred_all_kernel<<<dim3(NB/64, 1), 256, 0, stream>>>(hcur, 0, 0, Wdt, bd, out);
    for (int s = 1; s < OUTS; ++s){
      lstm_step_kernel<0><<<512, 256, 0, stream>>>(hcur, hnxt, c, Utap, b2, nullptr, nullptr);
      bf16* tmp = hcur; hcur = hnxt; hnxt = tmp;
      pred_all_kernel<<<dim3(NB/64, 1), 256, 0, stream>>>(hcur, 0, s, Wdt, bd, out);
    }
  }
}